// Round 11
// baseline (324.184 us; speedup 1.0000x reference)
//
#include <hip/hip_runtime.h>
#include <math.h>

#define NB 32        // batches
#define NP 512       // N == M == 512
#define RG4 4        // blocks (gang members) per batch  [R11: was 8]
#define RPB4 128     // rows per block
#define NT 1024      // threads per block (16 waves)
#define ITERS 50
#define EPSV   0.05f
#define INVEPS 20.0f

typedef unsigned long long u64;
typedef unsigned int u32;

// ws layout: pack[2][NB][RG4][NP] u32 (512 KB), then epi[NB][RG4] float2.
// Poison safety: 0xAAAAAAAA low 3 bits = 2; tag set {1,3,4,5,6,7} never
// contains 2 and all tags in any 6-window distinct. epi tag 51.0f != poison.
#define PAR_STRIDE3 (NB*RG4*NP)     // 65536 u32 per parity buffer
#define N_PACK3 (2*PAR_STRIDE3)     // 512 KB

// ---- relaxed agent-scope (device-coherent, IC) primitives ----
// R6 proved agent/IC is the ONLY working CU-to-CU transport on gfx950.
__device__ __forceinline__ void st32(u32* p, u32 v) {
  __hip_atomic_store(p, v, __ATOMIC_RELAXED, __HIP_MEMORY_SCOPE_AGENT);
}
__device__ __forceinline__ u32 ld32(const u32* p) {
  return __hip_atomic_load(p, __ATOMIC_RELAXED, __HIP_MEMORY_SCOPE_AGENT);
}
__device__ __forceinline__ void st64f(float2* p, float tag, float val) {
  union { float2 f; u64 u; } c; c.f = make_float2(tag, val);
  __hip_atomic_store((u64*)p, c.u, __ATOMIC_RELAXED, __HIP_MEMORY_SCOPE_AGENT);
}
__device__ __forceinline__ float2 ld64f(const float2* p) {
  union { u64 u; float2 f; } c;
  c.u = __hip_atomic_load((const u64*)p, __ATOMIC_RELAXED, __HIP_MEMORY_SCOPE_AGENT);
  return c.f;
}

// tag for iteration k: nibble LUT over k%6 -> {1,3,4,5,6,7} (proven r12/r14)
__device__ __forceinline__ u32 tag_of(int k) {
  return (0x765431u >> (4 * (k % 6))) & 0xFu;
}
// pack fp32 value with tag in low 3 mantissa bits (<=7 ulp perturbation)
__device__ __forceinline__ u32 pack_slot(float v, u32 tag) {
  return (__float_as_uint(v) & ~7u) | tag;
}

// ---------------- single fused kernel: setup + 50 linear-Sinkhorn iters + ot ----
// R11: GANG-SIZE probe. 4 blocks x 1024 threads per batch (was 8 x 512).
// Falsification ledger: congestion (R3), sampling (R5), medium (R1/R6),
// store path (R10), chain pairing (R9) all null/negative; post-publish spec
// (R7) = -6.4us. Last un-isolated V-parameter: PEER COUNT. Evidence it
// matters: R9's 15-peer rendezvous cost 3.26us/iter vs R7's 7-peer 2.72us.
// Mechanism: V = slowest-of-G publisher commit (E[max] skew) + convergence
// over G-1 streams. RG 8->4 halves both terms' inputs.
// Per-thread work is IDENTICAL to R7 (64-elem row cache, 64-elem col cache;
// B uses 8 threads/row; C splits each col's 128-row dot across 2 threads
// with one LDS combine). Grid = 128 blocks, 1 block/CU co-resident ->
// spin rendezvous deadlock-free with wide margin.
__global__ __launch_bounds__(NT) void emd_kernel(
    const float* __restrict__ a_mask, const float* __restrict__ pc_a,
    const float* __restrict__ b_mask, const float* __restrict__ pc_b,
    u32* __restrict__ pack, float2* __restrict__ epi,
    float* __restrict__ out)
{
  const int rb = blockIdx.x;         // 0..127
  const int b  = rb >> 2;            // batch
  const int g  = rb & 3;             // gang member 0..3
  const int t  = threadIdx.x;        // 0..1023
  const int chunk = t & 7;           // 8 threads per row (B)
  const int lrow  = t >> 3;          // local row 0..127
  const int grow  = g*RPB4 + lrow;   // global row 0..511
  const int ct    = t & 511;         // col owned in C/gather
  const int h     = t >> 9;          // row-half 0/1 for C
  const int lane  = t & 63, wid = t >> 6;   // wid 0..15

  __shared__ __align__(16) float rho_l[NP];   // exp(logv)
  __shared__ __align__(16) float bw_l[NP];    // col masses
  __shared__ __align__(16) float u_l[RPB4];   // exp(logu), 128 rows
  __shared__ __align__(16) float sm[NP];      // aw
  __shared__ __align__(16) float scc[NP];     // C half-combine
  __shared__ float red[16];

  float4 eKreg[16];     // row slice: row=grow, cols 32*cc+4*chunk+e (64 f)
  float  eKcol[64];     // col slice: col=ct, rows g*128 + h*64 + i (64 f)
  float  aw_r, bw_t, hub = 0.f;

  u32* ownp = pack + ((size_t)(b*RG4 + g))*NP + ct;   // h==0 publishes
  const u32* base0 = pack + (size_t)b*RG4*NP + ct;

  // ================= setup: masses, huber, expK caches =================
  {
    float apt = 0.f, bpt = 0.f;
    if (t < NP) {
      apt = a_mask[b*NP+t] * pc_a[((size_t)b*NP+t)*3+2];
      bpt = b_mask[b*NP+t] * pc_b[((size_t)b*NP+t)*3+2];
      float ra = apt, rv = bpt;
      #pragma unroll
      for (int o = 32; o; o >>= 1) { ra += __shfl_xor(ra, o); rv += __shfl_xor(rv, o); }
      if (lane == 0) { red[wid] = ra; red[8+wid] = rv; }   // waves 0..7
    }
    __syncthreads();
    float asum = 0.f, bsum = 0.f;
    #pragma unroll
    for (int w = 0; w < 8; ++w) { asum += red[w]; bsum += red[8+w]; }
    const float e = asum - bsum, ae = fabsf(e);
    hub = (ae <= 1.f) ? 0.5f*e*e : (ae - 0.5f);
    if (t < NP) {
      sm[t]   = (apt > 0.f) ? apt/asum : 0.f;   // aw
      bw_l[t] = (bpt > 0.f) ? bpt/bsum : 0.f;
      rho_l[t] = 1.f;                            // rho(0)
    }
    __syncthreads();
    aw_r = sm[grow];
    bw_t = bw_l[ct];
    const float ax = pc_a[((size_t)b*NP+grow)*3+0];
    const float ay = pc_a[((size_t)b*NP+grow)*3+1];
    const bool  va = aw_r > 0.f;
    #pragma unroll
    for (int cc = 0; cc < 16; ++cc) {
      float r[4];
      #pragma unroll
      for (int e2 = 0; e2 < 4; ++e2) {
        const int col = 32*cc + 4*chunk + e2;
        const float bx = pc_b[((size_t)b*NP+col)*3+0];
        const float by = pc_b[((size_t)b*NP+col)*3+1];
        const bool  vb = bw_l[col] > 0.f;
        const float dx = ax-bx, dy = ay-by;
        const float d  = sqrtf(dx*dx + dy*dy + 1e-12f);
        r[e2] = (va && vb) ? __expf((-INVEPS)*d) : 1.f;   // K=0 for masked pairs
      }
      eKreg[cc] = make_float4(r[0], r[1], r[2], r[3]);
    }
    const float bx0 = pc_b[((size_t)b*NP+ct)*3+0];
    const float by0 = pc_b[((size_t)b*NP+ct)*3+1];
    const bool  vb0 = bw_t > 0.f;
    #pragma unroll
    for (int i = 0; i < 64; ++i) {
      const int row = g*RPB4 + h*64 + i;
      const float axi = pc_a[((size_t)b*NP+row)*3+0];  // wave-uniform -> scalar
      const float ayi = pc_a[((size_t)b*NP+row)*3+1];
      const bool  vai = sm[row] > 0.f;
      const float dx = axi-bx0, dy = ayi-by0;
      const float d  = sqrtf(dx*dx + dy*dy + 1e-12f);
      eKcol[i] = (vai && vb0) ? __expf((-INVEPS)*d) : 1.f;
    }
    __syncthreads();
  }

  // ================= main loop =================
  for (int k = 1; k <= ITERS; ++k) {
    const u32 tag = tag_of(k);
    const size_t po = (size_t)(k & 1) * (size_t)PAR_STRIDE3;

    // ---- B: u(k) = aw / sum_j ek*rho(k-1)   (all 1024 threads, 8/row)
    {
      const float4* r4p = (const float4*)rho_l;
      float dot = 0.f;
      #pragma unroll
      for (int cc = 0; cc < 16; ++cc) {
        const float4 g4 = r4p[8*cc + chunk];
        const float4 kk = eKreg[cc];
        dot += kk.x*g4.x + kk.y*g4.y + kk.z*g4.z + kk.w*g4.w;
      }
      #pragma unroll
      for (int o = 4; o; o >>= 1) dot += __shfl_xor(dot, o);   // 8-lane reduce
      if (chunk == 0) u_l[lrow] = aw_r / fmaxf(dot, 1e-38f);
    }
    __syncthreads();   // u_l ready (also: all rho_l reads done)

    // ---- C: col partial over 128 own rows, split h=0/1 (64 rows each)
    float sc;
    {
      const float4* u4p = (const float4*)u_l;
      float s = 0.f;
      #pragma unroll
      for (int i4 = 0; i4 < 16; ++i4) {
        const float4 uu = u4p[h*16 + i4];
        s += eKcol[4*i4+0]*uu.x + eKcol[4*i4+1]*uu.y
           + eKcol[4*i4+2]*uu.z + eKcol[4*i4+3]*uu.w;
      }
      sc = s;
      if (h == 1) scc[ct] = s;
    }
    __syncthreads();   // scc ready

    // ---- publish + gather (h==0 threads own the cols; h==1 park at barrier)
    if (h == 0) {
      const float stot = sc + scc[ct];
      st32(ownp + po, pack_slot(stot, tag));

      // speculative gang issue, POST-publish (R7-proven timing)
      u32 q[RG4];
      #pragma unroll
      for (int r = 0; r < RG4; ++r)
        if (r != g) q[r] = ld32(base0 + po + (size_t)r*NP);

      unsigned pend = 0xFu & ~(1u << g);
      long long sweeps = 0;
      while (true) {
        unsigned np = 0;
        #pragma unroll
        for (int r = 0; r < RG4; ++r)
          if ((pend >> r) & 1u)
            if ((q[r] & 7u) != tag) np |= (1u << r);
        pend = np;
        if (!pend) break;
        #pragma unroll
        for (int r = 0; r < RG4; ++r)        // re-issue pending together;
          if ((pend >> r) & 1u)              // IC RT is the natural backoff
            q[r] = ld32(base0 + po + (size_t)r*NP);
        if (++sweeps > (1LL<<22)) break;     // fail visibly, never hang
      }
      float S = stot;
      #pragma unroll
      for (int r = 0; r < RG4; ++r)
        if (r != g) S += __uint_as_float(q[r]);   // <=7 ulp tag noise
      rho_l[ct] = bw_t / fmaxf(S, 1e-38f);
    }
    __syncthreads();   // rho_l(k) ready for next B / epilogue
  }

  // ---- epilogue: ot partial = sum d^2 * u_i * ek * rho_j over my row slice
  float acc = 0.f;
  {
    const float ur = u_l[lrow];                  // u(50)
    const float4* r4p = (const float4*)rho_l;    // rho(50)
    #pragma unroll
    for (int cc = 0; cc < 16; ++cc) {
      const float4 g4 = r4p[8*cc + chunk];
      const float4 kk = eKreg[cc];
      const float ek[4] = {kk.x, kk.y, kk.z, kk.w};
      const float vv[4] = {g4.x, g4.y, g4.z, g4.w};
      #pragma unroll
      for (int e2 = 0; e2 < 4; ++e2) {
        const float lk = __logf(fmaxf(ek[e2], 1e-38f));  // d = -EPS*lk; masked: lk=0 -> d2=0
        const float d2 = (EPSV*lk)*(EPSV*lk);
        const float v  = d2 * ur * ek[e2] * vv[e2];
        acc += (ek[e2] > 0.f) ? v : 0.f;
      }
    }
  }
  // wave-reduce 16 waves -> red, block sum -> tagged epi, g==0 gathers
  #pragma unroll
  for (int o = 32; o; o >>= 1) acc += __shfl_xor(acc, o);
  __syncthreads();               // red[] free (setup use done)
  if (lane == 0) red[wid] = acc;
  __syncthreads();
  if (t == 0) {
    float v = 0.f;
    #pragma unroll
    for (int w = 0; w < 16; ++w) v += red[w];
    st64f(epi + (size_t)b*RG4 + g, 51.f, v);
  }
  if (g == 0 && t < RG4) {       // gather: 4 lanes, poll + shfl-reduce
    float2 pr;
    long long spins = 0;
    do {
      pr = ld64f(epi + (size_t)b*RG4 + t);
      if (pr.x == 51.f) break;
      __builtin_amdgcn_s_sleep(1);
    } while (++spins < (1LL<<26));
    float v = pr.y;
    #pragma unroll
    for (int o = 2; o; o >>= 1) v += __shfl_xor(v, o);
    if (t == 0) out[b] = v + hub;
  }
}

extern "C" void kernel_launch(void* const* d_in, const int* in_sizes, int n_in,
                              void* d_out, int out_size, void* d_ws, size_t ws_size,
                              hipStream_t stream) {
  const float* a_mask = (const float*)d_in[0];
  const float* pc_a   = (const float*)d_in[1];
  const float* b_mask = (const float*)d_in[2];
  const float* pc_b   = (const float*)d_in[3];
  float* out = (float*)d_out;
  u32*    pack = (u32*)d_ws;                  // 512 KB
  float2* epi  = (float2*)(pack + N_PACK3);   // + 1 KB
  (void)in_sizes; (void)n_in; (void)out_size; (void)ws_size;

  emd_kernel<<<NB*RG4, NT, 0, stream>>>(a_mask, pc_a, b_mask, pc_b,
                                        pack, epi, out);
}

// Round 12
// 196.226 us; speedup vs baseline: 1.6521x; 1.6521x over previous
//
#include <hip/hip_runtime.h>
#include <math.h>

#define NB 32        // batches
#define NP 512       // N == M == 512
#define RG 8         // row-groups (blocks) per batch
#define RPB 64       // rows per block
#define ITERS 50
#define EPSV   0.05f
#define INVEPS 20.0f

typedef unsigned long long u64;
typedef unsigned int u32;

// ws layout: pack[2][NB][RG][NP] u32 (row-major: each 512-col stream is a
// contiguous single-writer array -> no false sharing), then epi[NB][RG] float2.
// Poison safety: 0xAAAAAAAA low 3 bits = 2; tag set {1,3,4,5,6,7} never
// contains 2 and tag(k) != tag(k-2) (k mod 6 LUT). epi tag 51.0f != poison.
#define N_PACK (2*NB*RG*NP)

// ---- relaxed agent-scope (device-coherent, IC) primitives ----
// R6 proved agent/IC is the ONLY working CU-to-CU transport on gfx950:
// plain-store/sc0-load pairs serve stale hits indefinitely.
__device__ __forceinline__ void st32(u32* p, u32 v) {
  __hip_atomic_store(p, v, __ATOMIC_RELAXED, __HIP_MEMORY_SCOPE_AGENT);
}
__device__ __forceinline__ u32 ld32(const u32* p) {
  return __hip_atomic_load(p, __ATOMIC_RELAXED, __HIP_MEMORY_SCOPE_AGENT);
}
__device__ __forceinline__ void st64f(float2* p, float tag, float val) {
  union { float2 f; u64 u; } c; c.f = make_float2(tag, val);
  __hip_atomic_store((u64*)p, c.u, __ATOMIC_RELAXED, __HIP_MEMORY_SCOPE_AGENT);
}
__device__ __forceinline__ float2 ld64f(const float2* p) {
  union { u64 u; float2 f; } c;
  c.u = __hip_atomic_load((const u64*)p, __ATOMIC_RELAXED, __HIP_MEMORY_SCOPE_AGENT);
  return c.f;
}

// tag for iteration k: nibble LUT over k%6 -> {1,3,4,5,6,7} (proven r12/r14)
__device__ __forceinline__ u32 tag_of(int k) {
  return (0x765431u >> (4 * (k % 6))) & 0xFu;
}
// pack fp32 value with tag in low 3 mantissa bits (<=7 ulp perturbation)
__device__ __forceinline__ u32 pack_slot(float v, u32 tag) {
  return (__float_as_uint(v) & ~7u) | tag;
}

// ---------------- single fused kernel: setup + 50 linear-Sinkhorn iters + ot ----
// ONE batch per 512-thread block, 64 rows each, RG=8 blocks/batch, grid=256
// (1 block/CU, all resident -> spin rendezvous deadlock-free).
//
// R12 = FINAL: R7 champion restored verbatim (147.3us measured). Session
// falsification ledger: medium (R1/R6), poll bandwidth (R3), sampling period
// (R5), store path / atomic-exchange publish (R10), in-block chain pairing
// (R9), gang size (R9 up: worse; R11 down: register-wall, spills at 64 VGPR).
// Only win: post-publish speculative issue (R7, -6.4us vs R0).
// Structural floor: 50 strictly-sequential inter-block rendezvous (the
// K^T u col-sum is the sole exchange/iter — one window, minimal payload),
// each bounded by agent-scope publish->visible+discovered ~2.5us on the IC
// fabric (measured consistently by three protocols: R0/R3/R7). 50 x ~2.9us
// + ~10us setup/epilogue ~= 147us. RG=8 @ 512thr is the unique geometry
// fitting the 2x64-float per-thread K-cache in registers (R11 proved).
__global__ __launch_bounds__(NP) void emd_kernel(
    const float* __restrict__ a_mask, const float* __restrict__ pc_a,
    const float* __restrict__ b_mask, const float* __restrict__ pc_b,
    u32* __restrict__ pack, float2* __restrict__ epi,
    float* __restrict__ out)
{
  const int rb = blockIdx.x;
  const int b  = rb >> 3;            // batch (contiguous 8-block ranges)
  const int rg = rb & 7;             // row-group 0..7
  const int t  = threadIdx.x;
  const int chunk = t & 7;           // 8 threads per row
  const int lrow  = t >> 3;          // local row 0..63
  const int grow  = rg*RPB + lrow;
  const int lane  = t & 63, wid = t >> 6;

  __shared__ __align__(16) float rho_l[NP];   // exp(logv)
  __shared__ __align__(16) float bw_l[NP];    // col masses
  __shared__ __align__(16) float u_l[RPB];    // exp(logu)
  __shared__ __align__(16) float sm[NP];      // setup aw / epilogue scratch
  __shared__ float red[16];

  float4 eKreg[16];     // row slice: row=grow, cols 32*cc+4*chunk+e
  float  eKcol[RPB];    // col slice: col=t, rows rg*64+i
  float  aw_r, bw_t, hub = 0.f;

  // ================= setup: masses, huber, expK caches =================
  {
    const float apt = a_mask[b*NP+t] * pc_a[((size_t)b*NP+t)*3+2];
    const float bpt = b_mask[b*NP+t] * pc_b[((size_t)b*NP+t)*3+2];
    float ra = apt, rv = bpt;
    #pragma unroll
    for (int o = 32; o; o >>= 1) { ra += __shfl_xor(ra, o); rv += __shfl_xor(rv, o); }
    if (lane == 0) { red[wid] = ra; red[8+wid] = rv; }
    __syncthreads();
    float asum = 0.f, bsum = 0.f;
    #pragma unroll
    for (int w = 0; w < 8; ++w) { asum += red[w]; bsum += red[8+w]; }
    const float e = asum - bsum, ae = fabsf(e);
    hub = (ae <= 1.f) ? 0.5f*e*e : (ae - 0.5f);
    sm[t]   = (apt > 0.f) ? apt/asum : 0.f;   // aw
    bw_l[t] = (bpt > 0.f) ? bpt/bsum : 0.f;
    __syncthreads();
    aw_r = sm[grow];
    bw_t = bw_l[t];
    const float ax = pc_a[((size_t)b*NP+grow)*3+0];
    const float ay = pc_a[((size_t)b*NP+grow)*3+1];
    const bool  va = aw_r > 0.f;
    #pragma unroll
    for (int cc = 0; cc < 16; ++cc) {
      float r[4];
      #pragma unroll
      for (int e2 = 0; e2 < 4; ++e2) {
        const int col = 32*cc + 4*chunk + e2;
        const float bx = pc_b[((size_t)b*NP+col)*3+0];
        const float by = pc_b[((size_t)b*NP+col)*3+1];
        const bool  vb = bw_l[col] > 0.f;
        const float dx = ax-bx, dy = ay-by;
        const float d  = sqrtf(dx*dx + dy*dy + 1e-12f);
        r[e2] = (va && vb) ? __expf((-INVEPS)*d) : 1.f;   // K=0 for masked pairs
      }
      eKreg[cc] = make_float4(r[0], r[1], r[2], r[3]);
    }
    const float bx0 = pc_b[((size_t)b*NP+t)*3+0];
    const float by0 = pc_b[((size_t)b*NP+t)*3+1];
    const bool  vb0 = bw_t > 0.f;
    #pragma unroll
    for (int i = 0; i < RPB; ++i) {
      const int row = rg*RPB + i;
      const float axi = pc_a[((size_t)b*NP+row)*3+0];  // wave-uniform -> scalar loads
      const float ayi = pc_a[((size_t)b*NP+row)*3+1];
      const bool  vai = sm[row] > 0.f;
      const float dx = axi-bx0, dy = ayi-by0;
      const float d  = sqrtf(dx*dx + dy*dy + 1e-12f);
      eKcol[i] = (vai && vb0) ? __expf((-INVEPS)*d) : 1.f;
    }
    rho_l[t] = 1.f;     // rho(0) = exp(logv=0) = 1
    __syncthreads();
  }

  // ================= main loop =================
  for (int k = 1; k <= ITERS; ++k) {
    const u32 tag = tag_of(k);
    const int par = k & 1;
    const u32* base = pack + ((size_t)par*NB + b)*RG*NP + t;

    // ---- B: u(k) = aw / sum_j ek*rho(k-1)
    {
      const float4* r4p = (const float4*)rho_l;
      float dot = 0.f;
      #pragma unroll
      for (int cc = 0; cc < 16; ++cc) {
        const float4 g4 = r4p[8*cc + chunk];
        const float4 kk = eKreg[cc];
        dot += kk.x*g4.x + kk.y*g4.y + kk.z*g4.z + kk.w*g4.w;
      }
      #pragma unroll
      for (int o = 4; o; o >>= 1) dot += __shfl_xor(dot, o);   // 8-lane row reduce
      if (chunk == 0) u_l[lrow] = aw_r / fmaxf(dot, 1e-38f);
    }
    __syncthreads();   // u_l ready (also: all rho_l reads done)

    // ---- C: publish packed col partial s(k) for col t; keep own value local
    float sc_own;
    {
      const float4* u4p = (const float4*)u_l;
      float sc = 0.f;
      #pragma unroll
      for (int i4 = 0; i4 < 16; ++i4) {
        const float4 uu = u4p[i4];
        sc += eKcol[4*i4+0]*uu.x + eKcol[4*i4+1]*uu.y
            + eKcol[4*i4+2]*uu.z + eKcol[4*i4+3]*uu.w;
      }
      sc_own = sc;
      st32(pack + (((size_t)par*NB + b)*RG + rg)*NP + t, pack_slot(sc, tag));
    }

    // ---- speculative gang issue, POST-publish (R7's win): samples the IC
    // at the instant near-lockstep peers are publishing too, so the first
    // check below catches most of them.
    u32 q[RG];
    #pragma unroll
    for (int r = 0; r < RG; ++r)
      if (r != rg) q[r] = ld32(base + (size_t)r*NP);

    // ---- A: check results; sleep-free gang re-poll of laggards (R0-proven:
    // polls carry the data; the ~600cy IC RT is the natural backoff)
    {
      unsigned pend = 0xFFu & ~(1u << rg);
      long long sweeps = 0;
      while (true) {
        unsigned np = 0;
        #pragma unroll
        for (int r = 0; r < RG; ++r)
          if ((pend >> r) & 1u)
            if ((q[r] & 7u) != tag) np |= (1u << r);
        pend = np;
        if (!pend) break;
        #pragma unroll
        for (int r = 0; r < RG; ++r)        // re-issue ALL pending together
          if ((pend >> r) & 1u)
            q[r] = ld32(base + (size_t)r*NP);
        if (++sweeps > (1LL<<24)) break;    // fail visibly, never hang
      }
      float S = sc_own;
      #pragma unroll
      for (int r = 0; r < RG; ++r)
        if (r != rg) S += __uint_as_float(q[r]);   // <=7 ulp tag noise
      rho_l[t] = bw_t / fmaxf(S, 1e-38f);
    }
    __syncthreads();   // rho_l(k) ready for next B / epilogue
  }

  // ---- epilogue: ot partial = sum d^2 * u_i * ek * rho_j over my row slice
  float acc = 0.f;
  {
    const float ur = u_l[lrow];                  // u(50)
    const float4* r4p = (const float4*)rho_l;    // rho(50)
    #pragma unroll
    for (int cc = 0; cc < 16; ++cc) {
      const float4 g4 = r4p[8*cc + chunk];
      const float4 kk = eKreg[cc];
      const float ek[4] = {kk.x, kk.y, kk.z, kk.w};
      const float vv[4] = {g4.x, g4.y, g4.z, g4.w};
      #pragma unroll
      for (int e2 = 0; e2 < 4; ++e2) {
        const float lk = __logf(fmaxf(ek[e2], 1e-38f));  // d = -EPS*lk; masked: lk=0 -> d2=0
        const float d2 = (EPSV*lk)*(EPSV*lk);
        const float v  = d2 * ur * ek[e2] * vv[e2];
        acc += (ek[e2] > 0.f) ? v : 0.f;
      }
    }
  }
  // block-reduce, publish tagged epi, rg==0 gathers
  sm[t] = acc;
  __syncthreads();
  if (t < 64) {
    float v = 0.f;
    #pragma unroll
    for (int q2 = 0; q2 < 8; ++q2) v += sm[t*8+q2];
    #pragma unroll
    for (int o = 32; o; o >>= 1) v += __shfl_xor(v, o);
    if (t == 0) st64f(epi + (size_t)b*RG + rg, 51.f, v);
  }
  if (rg == 0 && t < RG) {     // gather: 8 lanes, poll + shfl-reduce
    float2 pr;
    long long spins = 0;
    do {
      pr = ld64f(epi + (size_t)b*RG + t);
      if (pr.x == 51.f) break;
      __builtin_amdgcn_s_sleep(1);
    } while (++spins < (1LL<<27));
    float v = pr.y;
    #pragma unroll
    for (int o = 4; o; o >>= 1) v += __shfl_xor(v, o);
    if (t == 0) out[b] = v + hub;
  }
}

extern "C" void kernel_launch(void* const* d_in, const int* in_sizes, int n_in,
                              void* d_out, int out_size, void* d_ws, size_t ws_size,
                              hipStream_t stream) {
  const float* a_mask = (const float*)d_in[0];
  const float* pc_a   = (const float*)d_in[1];
  const float* b_mask = (const float*)d_in[2];
  const float* pc_b   = (const float*)d_in[3];
  float* out = (float*)d_out;
  u32*    pack = (u32*)d_ws;                 // 1 MiB
  float2* epi  = (float2*)(pack + N_PACK);   // + 2 KiB
  (void)in_sizes; (void)n_in; (void)out_size; (void)ws_size;

  emd_kernel<<<NB*RG, NP, 0, stream>>>(a_mask, pc_a, b_mask, pc_b,
                                       pack, epi, out);
}